// Round 2
// baseline (456.279 us; speedup 1.0000x reference)
//
#include <hip/hip_runtime.h>
#include <math.h>

// Weighted Procrustes (Kabsch), two-phase:
//  Phase 1: per-batch streaming reduction (one 512-thread block per batch)
//           -> 16 sums per batch into workspace. Pure BW kernel, no epilogue.
//  Phase 2: 8192 independent Horn-quaternion solves, one per thread.

constexpr int kB = 8192;
constexpr int kN = 2048;
constexpr float kEps = 1e-5f;

__global__ __launch_bounds__(512) void wproc_reduce(
    const float* __restrict__ src,
    const float* __restrict__ src_corr,
    const float* __restrict__ weights,
    float* __restrict__ ws)
{
    const int b = blockIdx.x;
    const int tid = threadIdx.x;               // 0..511, one float4 column each
    const float* arow = src + (size_t)b * 3 * kN;
    const float* brow = src_corr + (size_t)b * 3 * kN;

    const float4 w  = reinterpret_cast<const float4*>(weights + (size_t)b * kN)[tid];
    const float4 ax = reinterpret_cast<const float4*>(arow)[tid];
    const float4 ay = reinterpret_cast<const float4*>(arow + kN)[tid];
    const float4 az = reinterpret_cast<const float4*>(arow + 2 * kN)[tid];
    const float4 bx = reinterpret_cast<const float4*>(brow)[tid];
    const float4 by = reinterpret_cast<const float4*>(brow + kN)[tid];
    const float4 bz = reinterpret_cast<const float4*>(brow + 2 * kN)[tid];

    // acc: [0]=Σw [1..3]=Σw*a [4..6]=Σw*b [7..15]=Σw*a_d*b_e
    float acc[16];
    {
        const float wc[4]  = {w.x,  w.y,  w.z,  w.w};
        const float axc[4] = {ax.x, ax.y, ax.z, ax.w};
        const float ayc[4] = {ay.x, ay.y, ay.z, ay.w};
        const float azc[4] = {az.x, az.y, az.z, az.w};
        const float bxc[4] = {bx.x, bx.y, bx.z, bx.w};
        const float byc[4] = {by.x, by.y, by.z, by.w};
        const float bzc[4] = {bz.x, bz.y, bz.z, bz.w};
#pragma unroll
        for (int i = 0; i < 16; ++i) acc[i] = 0.f;
#pragma unroll
        for (int c = 0; c < 4; ++c) {
            const float ww  = wc[c];
            const float wax = ww * axc[c], way = ww * ayc[c], waz = ww * azc[c];
            const float bxx = bxc[c], byy = byc[c], bzz = bzc[c];
            acc[0]  += ww;
            acc[1]  += wax;       acc[2]  += way;       acc[3]  += waz;
            acc[4]  += ww * bxx;  acc[5]  += ww * byy;  acc[6]  += ww * bzz;
            acc[7]  += wax * bxx; acc[8]  += wax * byy; acc[9]  += wax * bzz;
            acc[10] += way * bxx; acc[11] += way * byy; acc[12] += way * bzz;
            acc[13] += waz * bxx; acc[14] += waz * byy; acc[15] += waz * bzz;
        }
    }

    // 64-lane butterfly
#pragma unroll
    for (int i = 0; i < 16; ++i) {
        float v = acc[i];
#pragma unroll
        for (int off = 32; off > 0; off >>= 1)
            v += __shfl_down(v, off, 64);
        acc[i] = v;
    }

    __shared__ float red[8][16];
    const int lane = tid & 63;
    const int wid  = tid >> 6;                 // 0..7
    if (lane == 0) {
#pragma unroll
        for (int i = 0; i < 16; ++i) red[wid][i] = acc[i];
    }
    __syncthreads();
    if (tid < 16) {
        float s = 0.f;
#pragma unroll
        for (int k = 0; k < 8; ++k) s += red[k][tid];
        ws[(size_t)b * 16 + tid] = s;
    }
}

__global__ __launch_bounds__(256) void wproc_solve(
    const float* __restrict__ ws,
    float* __restrict__ out)
{
    const int b = blockIdx.x * blockDim.x + threadIdx.x;
    if (b >= kB) return;

    float t[16];
#pragma unroll
    for (int i = 0; i < 4; ++i) {
        const float4 v = reinterpret_cast<const float4*>(ws + (size_t)b * 16)[i];
        t[4 * i] = v.x; t[4 * i + 1] = v.y; t[4 * i + 2] = v.z; t[4 * i + 3] = v.w;
    }

    const float W   = t[0];
    const float inv = 1.f / (W + kEps);
    const float S   = W * inv;
    float ca[3], cb[3];
#pragma unroll
    for (int d = 0; d < 3; ++d) { ca[d] = t[1 + d] * inv; cb[d] = t[4 + d] * inv; }

    float M[3][3];
    const float f2 = 2.f - S;
#pragma unroll
    for (int d = 0; d < 3; ++d)
#pragma unroll
        for (int e = 0; e < 3; ++e)
            M[d][e] = t[7 + 3 * d + e] * inv - ca[d] * cb[e] * f2;

    const float T  = M[0][0] + M[1][1] + M[2][2];
    const float cx = M[1][2] - M[2][1];
    const float cy = M[2][0] - M[0][2];
    const float cz = M[0][1] - M[1][0];
    float Nm[4][4];
    Nm[0][0] = T;
    Nm[0][1] = Nm[1][0] = cx;
    Nm[0][2] = Nm[2][0] = cy;
    Nm[0][3] = Nm[3][0] = cz;
    Nm[1][1] = 2.f * M[0][0] - T;
    Nm[2][2] = 2.f * M[1][1] - T;
    Nm[3][3] = 2.f * M[2][2] - T;
    Nm[1][2] = Nm[2][1] = M[0][1] + M[1][0];
    Nm[1][3] = Nm[3][1] = M[0][2] + M[2][0];
    Nm[2][3] = Nm[3][2] = M[1][2] + M[2][1];

    float Vv[4][4] = {{1,0,0,0},{0,1,0,0},{0,0,1,0},{0,0,0,1}};
    const int pp[6] = {0,0,0,1,1,2};
    const int qq[6] = {1,2,3,2,3,3};
    for (int sweep = 0; sweep < 6; ++sweep) {
        for (int r = 0; r < 6; ++r) {
            const int p = pp[r], q = qq[r];
            const float apq = Nm[p][q];
            if (fabsf(apq) < 1e-12f) continue;
            const float tau = (Nm[q][q] - Nm[p][p]) / (2.f * apq);
            const float tt  = copysignf(1.f, tau) / (fabsf(tau) + sqrtf(1.f + tau * tau));
            const float c   = 1.f / sqrtf(1.f + tt * tt);
            const float s   = tt * c;
            const float app = Nm[p][p], aqq = Nm[q][q];
            Nm[p][p] = app - tt * apq;
            Nm[q][q] = aqq + tt * apq;
            Nm[p][q] = Nm[q][p] = 0.f;
#pragma unroll
            for (int k = 0; k < 4; ++k) {
                if (k == p || k == q) continue;
                const float akp = Nm[k][p], akq = Nm[k][q];
                Nm[k][p] = Nm[p][k] = c * akp - s * akq;
                Nm[k][q] = Nm[q][k] = s * akp + c * akq;
            }
#pragma unroll
            for (int k = 0; k < 4; ++k) {
                const float vkp = Vv[k][p], vkq = Vv[k][q];
                Vv[k][p] = c * vkp - s * vkq;
                Vv[k][q] = s * vkp + c * vkq;
            }
        }
    }

    int jm = 0;
#pragma unroll
    for (int j = 1; j < 4; ++j) if (Nm[j][j] > Nm[jm][jm]) jm = j;
    float qw = Vv[0][jm], qx = Vv[1][jm], qy = Vv[2][jm], qz = Vv[3][jm];
    const float nq = 1.f / sqrtf(qw * qw + qx * qx + qy * qy + qz * qz);
    qw *= nq; qx *= nq; qy *= nq; qz *= nq;

    float R[3][3];
    R[0][0] = 1.f - 2.f * (qy * qy + qz * qz);
    R[0][1] = 2.f * (qx * qy - qw * qz);
    R[0][2] = 2.f * (qx * qz + qw * qy);
    R[1][0] = 2.f * (qx * qy + qw * qz);
    R[1][1] = 1.f - 2.f * (qx * qx + qz * qz);
    R[1][2] = 2.f * (qy * qz - qw * qx);
    R[2][0] = 2.f * (qx * qz - qw * qy);
    R[2][1] = 2.f * (qy * qz + qw * qx);
    R[2][2] = 1.f - 2.f * (qx * qx + qy * qy);

    float* ro = out + (size_t)b * 9;
#pragma unroll
    for (int i = 0; i < 3; ++i)
#pragma unroll
        for (int j = 0; j < 3; ++j)
            ro[3 * i + j] = R[i][j];

    float* to = out + (size_t)kB * 9 + (size_t)b * 3;
#pragma unroll
    for (int i = 0; i < 3; ++i)
        to[i] = cb[i] - (R[i][0] * ca[0] + R[i][1] * ca[1] + R[i][2] * ca[2]);
}

extern "C" void kernel_launch(void* const* d_in, const int* in_sizes, int n_in,
                              void* d_out, int out_size, void* d_ws, size_t ws_size,
                              hipStream_t stream) {
    const float* src      = (const float*)d_in[0];
    const float* src_corr = (const float*)d_in[1];
    const float* weights  = (const float*)d_in[2];
    float* out = (float*)d_out;
    float* ws  = (float*)d_ws;   // 8192*16 floats = 512 KB
    wproc_reduce<<<kB, 512, 0, stream>>>(src, src_corr, weights, ws);
    wproc_solve<<<(kB + 255) / 256, 256, 0, stream>>>(ws, out);
}

// Round 3
// 440.877 us; speedup vs baseline: 1.0349x; 1.0349x over previous
//
#include <hip/hip_runtime.h>
#include <math.h>

// Weighted Procrustes (Kabsch), two-phase:
//  Phase 1: per-batch streaming reduction, ONE WAVE (64 lanes) per batch.
//           Each lane handles 8 float4 per stream (64*8*4 = 2048 = N).
//           One 96-shuffle butterfly per 56 KB of data (8x less DS-pipe
//           pressure than the 8-wave-block version); no LDS, no barrier.
//  Phase 2: 8192 independent Horn-quaternion solves, one per thread.

constexpr int kB = 8192;
constexpr int kN = 2048;
constexpr float kEps = 1e-5f;
constexpr int kWavesPerBlock = 4;   // 256 threads, 4 independent batches

__global__ __launch_bounds__(256) void wproc_reduce(
    const float* __restrict__ src,
    const float* __restrict__ src_corr,
    const float* __restrict__ weights,
    float* __restrict__ ws)
{
    const int lane = threadIdx.x & 63;
    const int wave = threadIdx.x >> 6;
    const int b = blockIdx.x * kWavesPerBlock + wave;

    const float* arow = src + (size_t)b * 3 * kN;
    const float* brow = src_corr + (size_t)b * 3 * kN;
    const float4* w4  = reinterpret_cast<const float4*>(weights + (size_t)b * kN);
    const float4* ax4 = reinterpret_cast<const float4*>(arow);
    const float4* ay4 = reinterpret_cast<const float4*>(arow + kN);
    const float4* az4 = reinterpret_cast<const float4*>(arow + 2 * kN);
    const float4* bx4 = reinterpret_cast<const float4*>(brow);
    const float4* by4 = reinterpret_cast<const float4*>(brow + kN);
    const float4* bz4 = reinterpret_cast<const float4*>(brow + 2 * kN);

    // acc: [0]=Σw [1..3]=Σw*a [4..6]=Σw*b [7..15]=Σw*a_d*b_e
    float acc[16];
#pragma unroll
    for (int i = 0; i < 16; ++i) acc[i] = 0.f;

#pragma unroll 4
    for (int it = 0; it < kN / 4 / 64; ++it) {   // 8 iterations
        const int idx = it * 64 + lane;
        const float4 w  = w4[idx];
        const float4 ax = ax4[idx];
        const float4 ay = ay4[idx];
        const float4 az = az4[idx];
        const float4 bx = bx4[idx];
        const float4 by = by4[idx];
        const float4 bz = bz4[idx];
        const float wc[4]  = {w.x,  w.y,  w.z,  w.w};
        const float axc[4] = {ax.x, ax.y, ax.z, ax.w};
        const float ayc[4] = {ay.x, ay.y, ay.z, ay.w};
        const float azc[4] = {az.x, az.y, az.z, az.w};
        const float bxc[4] = {bx.x, bx.y, bx.z, bx.w};
        const float byc[4] = {by.x, by.y, by.z, by.w};
        const float bzc[4] = {bz.x, bz.y, bz.z, bz.w};
#pragma unroll
        for (int c = 0; c < 4; ++c) {
            const float ww  = wc[c];
            const float wax = ww * axc[c], way = ww * ayc[c], waz = ww * azc[c];
            const float bxx = bxc[c], byy = byc[c], bzz = bzc[c];
            acc[0]  += ww;
            acc[1]  += wax;                acc[2]  += way;                acc[3]  += waz;
            acc[4]  = fmaf(ww,  bxx, acc[4]);  acc[5]  = fmaf(ww,  byy, acc[5]);  acc[6]  = fmaf(ww,  bzz, acc[6]);
            acc[7]  = fmaf(wax, bxx, acc[7]);  acc[8]  = fmaf(wax, byy, acc[8]);  acc[9]  = fmaf(wax, bzz, acc[9]);
            acc[10] = fmaf(way, bxx, acc[10]); acc[11] = fmaf(way, byy, acc[11]); acc[12] = fmaf(way, bzz, acc[12]);
            acc[13] = fmaf(waz, bxx, acc[13]); acc[14] = fmaf(waz, byy, acc[14]); acc[15] = fmaf(waz, bzz, acc[15]);
        }
    }

    // one 64-lane butterfly per batch (amortized over the whole 56 KB)
#pragma unroll
    for (int i = 0; i < 16; ++i) {
        float v = acc[i];
#pragma unroll
        for (int off = 32; off > 0; off >>= 1)
            v += __shfl_down(v, off, 64);
        acc[i] = v;
    }

    if (lane == 0) {
        float4* o = reinterpret_cast<float4*>(ws + (size_t)b * 16);
        o[0] = make_float4(acc[0],  acc[1],  acc[2],  acc[3]);
        o[1] = make_float4(acc[4],  acc[5],  acc[6],  acc[7]);
        o[2] = make_float4(acc[8],  acc[9],  acc[10], acc[11]);
        o[3] = make_float4(acc[12], acc[13], acc[14], acc[15]);
    }
}

__global__ __launch_bounds__(256) void wproc_solve(
    const float* __restrict__ ws,
    float* __restrict__ out)
{
    const int b = blockIdx.x * blockDim.x + threadIdx.x;
    if (b >= kB) return;

    float t[16];
#pragma unroll
    for (int i = 0; i < 4; ++i) {
        const float4 v = reinterpret_cast<const float4*>(ws + (size_t)b * 16)[i];
        t[4 * i] = v.x; t[4 * i + 1] = v.y; t[4 * i + 2] = v.z; t[4 * i + 3] = v.w;
    }

    const float W   = t[0];
    const float inv = 1.f / (W + kEps);
    const float S   = W * inv;
    float ca[3], cb[3];
#pragma unroll
    for (int d = 0; d < 3; ++d) { ca[d] = t[1 + d] * inv; cb[d] = t[4 + d] * inv; }

    float M[3][3];
    const float f2 = 2.f - S;
#pragma unroll
    for (int d = 0; d < 3; ++d)
#pragma unroll
        for (int e = 0; e < 3; ++e)
            M[d][e] = t[7 + 3 * d + e] * inv - ca[d] * cb[e] * f2;

    const float T  = M[0][0] + M[1][1] + M[2][2];
    const float cx = M[1][2] - M[2][1];
    const float cy = M[2][0] - M[0][2];
    const float cz = M[0][1] - M[1][0];
    float Nm[4][4];
    Nm[0][0] = T;
    Nm[0][1] = Nm[1][0] = cx;
    Nm[0][2] = Nm[2][0] = cy;
    Nm[0][3] = Nm[3][0] = cz;
    Nm[1][1] = 2.f * M[0][0] - T;
    Nm[2][2] = 2.f * M[1][1] - T;
    Nm[3][3] = 2.f * M[2][2] - T;
    Nm[1][2] = Nm[2][1] = M[0][1] + M[1][0];
    Nm[1][3] = Nm[3][1] = M[0][2] + M[2][0];
    Nm[2][3] = Nm[3][2] = M[1][2] + M[2][1];

    float Vv[4][4] = {{1,0,0,0},{0,1,0,0},{0,0,1,0},{0,0,0,1}};
    const int pp[6] = {0,0,0,1,1,2};
    const int qq[6] = {1,2,3,2,3,3};
    for (int sweep = 0; sweep < 6; ++sweep) {
        for (int r = 0; r < 6; ++r) {
            const int p = pp[r], q = qq[r];
            const float apq = Nm[p][q];
            if (fabsf(apq) < 1e-12f) continue;
            const float tau = (Nm[q][q] - Nm[p][p]) / (2.f * apq);
            const float tt  = copysignf(1.f, tau) / (fabsf(tau) + sqrtf(1.f + tau * tau));
            const float c   = 1.f / sqrtf(1.f + tt * tt);
            const float s   = tt * c;
            const float app = Nm[p][p], aqq = Nm[q][q];
            Nm[p][p] = app - tt * apq;
            Nm[q][q] = aqq + tt * apq;
            Nm[p][q] = Nm[q][p] = 0.f;
#pragma unroll
            for (int k = 0; k < 4; ++k) {
                if (k == p || k == q) continue;
                const float akp = Nm[k][p], akq = Nm[k][q];
                Nm[k][p] = Nm[p][k] = c * akp - s * akq;
                Nm[k][q] = Nm[q][k] = s * akp + c * akq;
            }
#pragma unroll
            for (int k = 0; k < 4; ++k) {
                const float vkp = Vv[k][p], vkq = Vv[k][q];
                Vv[k][p] = c * vkp - s * vkq;
                Vv[k][q] = s * vkp + c * vkq;
            }
        }
    }

    int jm = 0;
#pragma unroll
    for (int j = 1; j < 4; ++j) if (Nm[j][j] > Nm[jm][jm]) jm = j;
    float qw = Vv[0][jm], qx = Vv[1][jm], qy = Vv[2][jm], qz = Vv[3][jm];
    const float nq = 1.f / sqrtf(qw * qw + qx * qx + qy * qy + qz * qz);
    qw *= nq; qx *= nq; qy *= nq; qz *= nq;

    float R[3][3];
    R[0][0] = 1.f - 2.f * (qy * qy + qz * qz);
    R[0][1] = 2.f * (qx * qy - qw * qz);
    R[0][2] = 2.f * (qx * qz + qw * qy);
    R[1][0] = 2.f * (qx * qy + qw * qz);
    R[1][1] = 1.f - 2.f * (qx * qx + qz * qz);
    R[1][2] = 2.f * (qy * qz - qw * qx);
    R[2][0] = 2.f * (qx * qz - qw * qy);
    R[2][1] = 2.f * (qy * qz + qw * qx);
    R[2][2] = 1.f - 2.f * (qx * qx + qy * qy);

    float* ro = out + (size_t)b * 9;
#pragma unroll
    for (int i = 0; i < 3; ++i)
#pragma unroll
        for (int j = 0; j < 3; ++j)
            ro[3 * i + j] = R[i][j];

    float* to = out + (size_t)kB * 9 + (size_t)b * 3;
#pragma unroll
    for (int i = 0; i < 3; ++i)
        to[i] = cb[i] - (R[i][0] * ca[0] + R[i][1] * ca[1] + R[i][2] * ca[2]);
}

extern "C" void kernel_launch(void* const* d_in, const int* in_sizes, int n_in,
                              void* d_out, int out_size, void* d_ws, size_t ws_size,
                              hipStream_t stream) {
    const float* src      = (const float*)d_in[0];
    const float* src_corr = (const float*)d_in[1];
    const float* weights  = (const float*)d_in[2];
    float* out = (float*)d_out;
    float* ws  = (float*)d_ws;   // 8192*16 floats = 512 KB
    wproc_reduce<<<kB / kWavesPerBlock, 64 * kWavesPerBlock, 0, stream>>>(src, src_corr, weights, ws);
    wproc_solve<<<(kB + 255) / 256, 256, 0, stream>>>(ws, out);
}